// Round 1
// baseline (3940.972 us; speedup 1.0000x reference)
//
#include <hip/hip_runtime.h>
#include <math.h>

// Problem constants
#define BATCH 2
#define SEQ   2048
#define DIM   2048
#define NH    16
#define HD    128
#define EPS   1e-6f

// ---------------------------------------------------------------------------
// Kernel 1/4: fp32 GEMM  C[M,N] = A[M,K] @ B[N,K]^T
// 64x64 block tile, 16x16 threads, 4x4 micro-tile (strided rows ty+16i /
// cols tx+16j so LDS reads within one instruction hit consecutive rows).
// LDS row stride 36 floats (9 float4s, odd) -> bank-conflict-free b128 reads.
// ---------------------------------------------------------------------------
#define GT 64
#define GK 32

__global__ __launch_bounds__(256) void gemm_abt(
    const float* __restrict__ A, const float* __restrict__ B,
    float* __restrict__ C, int M, int N, int K) {
  __shared__ float As[GT][GK + 4];
  __shared__ float Bs[GT][GK + 4];
  const int t = threadIdx.x;
  const int tx = t & 15, ty = t >> 4;
  const int bm = blockIdx.y * GT, bn = blockIdx.x * GT;
  float acc[4][4] = {};
  for (int k0 = 0; k0 < K; k0 += GK) {
    #pragma unroll
    for (int l = 0; l < 2; ++l) {
      int f = t + l * 256;
      int r = f >> 3, c = (f & 7) << 2;   // 8 float4 per 32-float row
      *(float4*)(&As[r][c]) = *(const float4*)(A + (size_t)(bm + r) * K + k0 + c);
      *(float4*)(&Bs[r][c]) = *(const float4*)(B + (size_t)(bn + r) * K + k0 + c);
    }
    __syncthreads();
    #pragma unroll
    for (int d = 0; d < GK; d += 4) {
      float4 a[4], b[4];
      #pragma unroll
      for (int i = 0; i < 4; ++i) a[i] = *(const float4*)(&As[ty + 16 * i][d]);
      #pragma unroll
      for (int j = 0; j < 4; ++j) b[j] = *(const float4*)(&Bs[tx + 16 * j][d]);
      #pragma unroll
      for (int i = 0; i < 4; ++i)
        #pragma unroll
        for (int j = 0; j < 4; ++j)
          acc[i][j] += a[i].x * b[j].x + a[i].y * b[j].y +
                       a[i].z * b[j].z + a[i].w * b[j].w;
    }
    __syncthreads();
  }
  #pragma unroll
  for (int i = 0; i < 4; ++i)
    #pragma unroll
    for (int j = 0; j < 4; ++j)
      C[(size_t)(bm + ty + 16 * i) * N + bn + tx + 16 * j] = acc[i][j];
}

// ---------------------------------------------------------------------------
// Kernel 2: fused RMSNorm + RoPE + head-transpose.
// qkv[b,s,6144] -> Qt/Kt/Vt [b,h,s,128].  One lane per rotation pair (2i,2i+1);
// wave64 shuffle-reduce for sum of squares (128 vals = 64 lanes x 2).
// Block = 256 threads = 4 waves; wave w handles heads w, w+4, w+8, w+12.
// ---------------------------------------------------------------------------
__global__ __launch_bounds__(256) void rmsrope(
    const float* __restrict__ qkv, const float* __restrict__ cosb,
    const float* __restrict__ sinb, float* __restrict__ Qt,
    float* __restrict__ Kt, float* __restrict__ Vt) {
  const int blk = blockIdx.x;           // b*SEQ + s
  const int b = blk >> 11, s = blk & (SEQ - 1);
  const int wave = threadIdx.x >> 6, lane = threadIdx.x & 63;
  const float* base = qkv + (size_t)blk * (3 * DIM);
  const float c  = cosb[s * HD + 2 * lane];   // cos[:, ::2] per reference
  const float sn = sinb[s * HD + 2 * lane];
  #pragma unroll
  for (int h = wave; h < NH; h += 4) {
    float2 q = *(const float2*)(base + h * HD + 2 * lane);
    float2 k = *(const float2*)(base + DIM + h * HD + 2 * lane);
    float2 v = *(const float2*)(base + 2 * DIM + h * HD + 2 * lane);
    float ssq = q.x * q.x + q.y * q.y;
    float ssk = k.x * k.x + k.y * k.y;
    #pragma unroll
    for (int off = 32; off >= 1; off >>= 1) {
      ssq += __shfl_xor(ssq, off, 64);
      ssk += __shfl_xor(ssk, off, 64);
    }
    float rq = rsqrtf(ssq * (1.0f / HD) + EPS);
    float rk = rsqrtf(ssk * (1.0f / HD) + EPS);
    float q1 = q.x * rq, q2 = q.y * rq;
    float k1 = k.x * rk, k2 = k.y * rk;
    size_t o = ((size_t)(b * NH + h) * SEQ + s) * HD + 2 * lane;
    *(float2*)(Qt + o) = make_float2(q1 * c - q2 * sn, q1 * sn + q2 * c);
    *(float2*)(Kt + o) = make_float2(k1 * c - k2 * sn, k1 * sn + k2 * c);
    *(float2*)(Vt + o) = v;
  }
}

// ---------------------------------------------------------------------------
// Kernel 3: flash attention, fp32, online softmax.
// One block per (b, h, 64-query tile); K/V chunks of 32.
// LDS tiles XOR-swizzled ([row][128] floats, float4 col ^ (row&7)) so both
// Q reads (4 consecutive rows broadcast x16) and K reads (16 consecutive
// rows) are conflict-free without padding. P-tile aliases K-tile (K fully
// consumed before P write; barrier between). Total LDS = exactly 64 KB.
// ---------------------------------------------------------------------------
__device__ __forceinline__ int sw128(int row, int c4) {
  return (row << 5) + (c4 ^ (row & 7));   // float4 index into [rows][128]f tile
}

__global__ __launch_bounds__(256) void flash_attn(
    const float* __restrict__ Qt, const float* __restrict__ Kt,
    const float* __restrict__ Vt, float* __restrict__ O) {
  __shared__ float4 Qs4[64 * 32];   // 32 KB
  __shared__ float4 Ks4[32 * 32];   // 16 KB (P-tile aliases this)
  __shared__ float4 Vs4[32 * 32];   // 16 KB
  float* Ps = (float*)Ks4;          // [64][36] floats = 9216 B <= 16384 B

  const int t = threadIdx.x;
  const int tx = t & 15, ty = t >> 4;
  const int q0 = blockIdx.x * 64;
  const int bh = blockIdx.z * NH + blockIdx.y;
  const float4* Qg = (const float4*)(Qt + ((size_t)bh * SEQ + q0) * HD);
  const float4* Kg = (const float4*)(Kt + (size_t)bh * SEQ * HD);
  const float4* Vg = (const float4*)(Vt + (size_t)bh * SEQ * HD);

  #pragma unroll
  for (int l = 0; l < 8; ++l) {        // Q tile: 64x128f = 2048 float4
    int f = t + l * 256;
    int r = f >> 5, c4 = f & 31;
    Qs4[sw128(r, c4)] = Qg[r * 32 + c4];
  }

  float m[4], lsum[4], acc[4][8];
  #pragma unroll
  for (int i = 0; i < 4; ++i) {
    m[i] = -INFINITY; lsum[i] = 0.f;
    #pragma unroll
    for (int dd = 0; dd < 8; ++dd) acc[i][dd] = 0.f;
  }
  const float scale = 0.08838834764831845f;  // 1/sqrt(128)

  for (int kk = 0; kk < SEQ; kk += 32) {
    __syncthreads();                       // prev PV done (first iter: Q staged)
    #pragma unroll
    for (int l = 0; l < 4; ++l) {          // K,V chunk: 32x128f = 1024 float4
      int f = t + l * 256;
      int r = f >> 5, c4 = f & 31;
      Ks4[sw128(r, c4)] = Kg[(kk + r) * 32 + c4];
      Vs4[sw128(r, c4)] = Vg[(kk + r) * 32 + c4];
    }
    __syncthreads();

    float sc[4][2] = {};
    #pragma unroll
    for (int d4 = 0; d4 < 32; ++d4) {
      float4 a[4], bb[2];
      #pragma unroll
      for (int i = 0; i < 4; ++i) a[i] = Qs4[sw128(ty + 16 * i, d4)];
      #pragma unroll
      for (int j = 0; j < 2; ++j) bb[j] = Ks4[sw128(tx + 16 * j, d4)];
      #pragma unroll
      for (int i = 0; i < 4; ++i)
        #pragma unroll
        for (int j = 0; j < 2; ++j)
          sc[i][j] += a[i].x * bb[j].x + a[i].y * bb[j].y +
                      a[i].z * bb[j].z + a[i].w * bb[j].w;
    }
    __syncthreads();                       // everyone done reading Ks (alias!)

    #pragma unroll
    for (int i = 0; i < 4; ++i) {
      float s0 = sc[i][0] * scale, s1 = sc[i][1] * scale;
      float mx = fmaxf(s0, s1);
      #pragma unroll
      for (int off = 8; off >= 1; off >>= 1) mx = fmaxf(mx, __shfl_xor(mx, off, 16));
      float mn = fmaxf(m[i], mx);
      float al = __expf(m[i] - mn);        // exp(-inf)=0 on first chunk
      float p0 = __expf(s0 - mn), p1 = __expf(s1 - mn);
      float rs = p0 + p1;
      #pragma unroll
      for (int off = 8; off >= 1; off >>= 1) rs += __shfl_xor(rs, off, 16);
      lsum[i] = lsum[i] * al + rs;
      m[i] = mn;
      Ps[(ty + 16 * i) * 36 + tx]      = p0;
      Ps[(ty + 16 * i) * 36 + tx + 16] = p1;
      #pragma unroll
      for (int dd = 0; dd < 8; ++dd) acc[i][dd] *= al;
    }
    __syncthreads();                       // P visible

    const float* Vsf = (const float*)Vs4;
    #pragma unroll 4
    for (int k = 0; k < 32; ++k) {
      float vv[8];
      #pragma unroll
      for (int dd = 0; dd < 8; ++dd) {
        int cc = tx + 16 * dd;
        vv[dd] = Vsf[sw128(k, cc >> 2) * 4 + (cc & 3)];
      }
      #pragma unroll
      for (int i = 0; i < 4; ++i) {
        float pk = Ps[(ty + 16 * i) * 36 + k];
        #pragma unroll
        for (int dd = 0; dd < 8; ++dd) acc[i][dd] += pk * vv[dd];
      }
    }
  }

  // epilogue: O[b, s, h*128+d]  (ready as A-matrix for the out-projection)
  #pragma unroll
  for (int i = 0; i < 4; ++i) {
    float inv = 1.0f / lsum[i];
    int row = q0 + ty + 16 * i;
    float* op = O + ((size_t)blockIdx.z * SEQ + row) * DIM + blockIdx.y * HD;
    #pragma unroll
    for (int dd = 0; dd < 8; ++dd) op[tx + 16 * dd] = acc[i][dd] * inv;
  }
}

// ---------------------------------------------------------------------------
// Launch
// ---------------------------------------------------------------------------
extern "C" void kernel_launch(void* const* d_in, const int* in_sizes, int n_in,
                              void* d_out, int out_size, void* d_ws, size_t ws_size,
                              hipStream_t stream) {
  const float* x     = (const float*)d_in[0];
  const float* cosb  = (const float*)d_in[1];
  const float* sinb  = (const float*)d_in[2];
  const float* Wqkv  = (const float*)d_in[3];
  const float* Wproj = (const float*)d_in[4];
  float* out = (float*)d_out;

  // workspace layout (fp32 elements):
  //   qkv : 4096*6144            = 25,165,824
  //   Qt  : 2*16*2048*128        =  8,388,608
  //   Kt  : 8,388,608    Vt : 8,388,608
  //   O   : aliases qkv (qkv fully consumed by rmsrope before flash writes O)
  float* qkv = (float*)d_ws;
  float* Qt  = qkv + (size_t)25165824;
  float* Kt  = Qt + (size_t)8388608;
  float* Vt  = Kt + (size_t)8388608;
  float* O   = qkv;

  const int M = BATCH * SEQ;  // 4096

  // 1) qkv = x @ W_qkv^T   [4096 x 6144]
  gemm_abt<<<dim3(3 * DIM / GT, M / GT), 256, 0, stream>>>(x, Wqkv, qkv, M, 3 * DIM, DIM);
  // 2) RMSNorm + RoPE + transpose to [b,h,s,d]
  rmsrope<<<dim3(BATCH * SEQ), 256, 0, stream>>>(qkv, cosb, sinb, Qt, Kt, Vt);
  // 3) flash attention -> O [b,s,h*d]
  flash_attn<<<dim3(SEQ / 64, NH, BATCH), 256, 0, stream>>>(Qt, Kt, Vt, O);
  // 4) out = O @ W_proj^T  [4096 x 2048]
  gemm_abt<<<dim3(DIM / GT, M / GT), 256, 0, stream>>>(O, Wproj, out, M, DIM, DIM);
}

// Round 2
// 1997.116 us; speedup vs baseline: 1.9733x; 1.9733x over previous
//
#include <hip/hip_runtime.h>
#include <math.h>

// Problem constants
#define BATCH 2
#define SEQ   2048
#define DIM   2048
#define NH    16
#define HD    128
#define EPS   1e-6f

typedef __bf16 bf16x8 __attribute__((ext_vector_type(8)));
typedef float  f32x4  __attribute__((ext_vector_type(4)));

// bf16 round-to-nearest-even split helpers
__device__ __forceinline__ unsigned short f2bf(float f) {
  union { float f; unsigned u; } v; v.f = f;
  unsigned r = v.u + 0x7FFFu + ((v.u >> 16) & 1u);
  return (unsigned short)(r >> 16);
}
__device__ __forceinline__ float bf2f(unsigned short h) {
  union { unsigned u; float f; } v; v.u = ((unsigned)h) << 16;
  return v.f;
}

// ---------------------------------------------------------------------------
// split fp32 -> (hi, lo) bf16.  4 floats/thread; grids sized exactly.
// ---------------------------------------------------------------------------
__global__ __launch_bounds__(256) void split_bf16(
    const float* __restrict__ in, unsigned short* __restrict__ hi,
    unsigned short* __restrict__ lo) {
  int i = blockIdx.x * 256 + threadIdx.x;
  float4 v = ((const float4*)in)[i];
  ushort4 h, l;
  h.x = f2bf(v.x); l.x = f2bf(v.x - bf2f(h.x));
  h.y = f2bf(v.y); l.y = f2bf(v.y - bf2f(h.y));
  h.z = f2bf(v.z); l.z = f2bf(v.z - bf2f(h.z));
  h.w = f2bf(v.w); l.w = f2bf(v.w - bf2f(h.w));
  ((ushort4*)hi)[i] = h;
  ((ushort4*)lo)[i] = l;
}

// ---------------------------------------------------------------------------
// Split-bf16 MFMA GEMM:  C[M,N] fp32 = (Ah+Al)[M,K] @ (Bh+Bl)[N,K]^T
// (lo*lo term dropped; ~2^-16 relative).  m97 structure: 128x128 tile, BK=32,
// 4 waves (2x2), 4x4 16x16x32 fragments per wave, global_load_lds width-16
// staging (lane-contiguous LDS tiles, no padding), 2-barrier K-loop.
// Per K-step/wave: 16 ds_read_b128 -> 48 MFMA.
// ---------------------------------------------------------------------------
#define BM 128
#define BN 128
#define BK 32

__global__ __launch_bounds__(256) void gemm_split(
    const unsigned short* __restrict__ Ahg, const unsigned short* __restrict__ Alg,
    const unsigned short* __restrict__ Bhg, const unsigned short* __restrict__ Blg,
    float* __restrict__ C, int M, int N, int K) {
  __shared__ __align__(16) unsigned short Ah[BM * BK];  // 8 KB each
  __shared__ __align__(16) unsigned short Al[BM * BK];
  __shared__ __align__(16) unsigned short Bh[BM * BK];
  __shared__ __align__(16) unsigned short Bl[BM * BK];

  const int t = threadIdx.x;
  const int w = t >> 6, lane = t & 63;
  const int bm = blockIdx.y * BM, bn = blockIdx.x * BN;
  const int wr = (w >> 1) * 64, wc = (w & 1) * 64;  // wave's 64x64 quadrant
  const int r16 = lane & 15, kg = lane >> 4;

  // wave w stages one whole 128x32 bf16 tile (8 issues x 1024 B)
  const unsigned short* gsrc;
  unsigned short* lbase;
  if (w == 0)      { gsrc = Ahg + (size_t)bm * K; lbase = Ah; }
  else if (w == 1) { gsrc = Alg + (size_t)bm * K; lbase = Al; }
  else if (w == 2) { gsrc = Bhg + (size_t)bn * K; lbase = Bh; }
  else             { gsrc = Blg + (size_t)bn * K; lbase = Bl; }
  const int srow = lane >> 2, scol = (lane & 3) << 3;  // lane's 8 bf16 within row

  f32x4 acc[4][4] = {};

  for (int k0 = 0; k0 < K; k0 += BK) {
    __syncthreads();  // previous compute done before LDS overwrite
    #pragma unroll
    for (int p = 0; p < 8; ++p) {
      const unsigned short* ga = gsrc + (size_t)(p * 16 + srow) * K + k0 + scol;
      __builtin_amdgcn_global_load_lds(
          (const __attribute__((address_space(1))) unsigned int*)ga,
          (__attribute__((address_space(3))) unsigned int*)(lbase + p * 512),
          16, 0, 0);
    }
    __syncthreads();  // drains vmcnt -> all 4 tiles visible

    bf16x8 ah[4], al[4], bh[4], bl[4];
    #pragma unroll
    for (int i = 0; i < 4; ++i) {
      ah[i] = *(const bf16x8*)(Ah + (wr + 16 * i + r16) * BK + kg * 8);
      al[i] = *(const bf16x8*)(Al + (wr + 16 * i + r16) * BK + kg * 8);
      bh[i] = *(const bf16x8*)(Bh + (wc + 16 * i + r16) * BK + kg * 8);
      bl[i] = *(const bf16x8*)(Bl + (wc + 16 * i + r16) * BK + kg * 8);
    }
    // 3 passes of 16 independent MFMAs (acc reuse distance 16 -> ILP)
    #pragma unroll
    for (int i = 0; i < 4; ++i)
      #pragma unroll
      for (int j = 0; j < 4; ++j)
        acc[i][j] = __builtin_amdgcn_mfma_f32_16x16x32_bf16(ah[i], bh[j], acc[i][j], 0, 0, 0);
    #pragma unroll
    for (int i = 0; i < 4; ++i)
      #pragma unroll
      for (int j = 0; j < 4; ++j)
        acc[i][j] = __builtin_amdgcn_mfma_f32_16x16x32_bf16(ah[i], bl[j], acc[i][j], 0, 0, 0);
    #pragma unroll
    for (int i = 0; i < 4; ++i)
      #pragma unroll
      for (int j = 0; j < 4; ++j)
        acc[i][j] = __builtin_amdgcn_mfma_f32_16x16x32_bf16(al[i], bh[j], acc[i][j], 0, 0, 0);
  }

  // C/D layout: col = lane&15, row = (lane>>4)*4 + reg   [m89-verified]
  #pragma unroll
  for (int i = 0; i < 4; ++i)
    #pragma unroll
    for (int j = 0; j < 4; ++j) {
      int col = bn + wc + 16 * j + r16;
      #pragma unroll
      for (int r = 0; r < 4; ++r) {
        int row = bm + wr + 16 * i + kg * 4 + r;
        C[(size_t)row * N + col] = acc[i][j][r];
      }
    }
}

// ---------------------------------------------------------------------------
// Fused RMSNorm + RoPE, IN PLACE on qkv[b,s,6144] (q and k halves only;
// v untouched).  One lane per rotation pair; wave64 shuffle reduce.
// ---------------------------------------------------------------------------
__global__ __launch_bounds__(256) void rmsrope_ip(
    float* __restrict__ qkv, const float* __restrict__ cosb,
    const float* __restrict__ sinb) {
  const int blk = blockIdx.x;           // b*SEQ + s
  const int s = blk & (SEQ - 1);
  const int wave = threadIdx.x >> 6, lane = threadIdx.x & 63;
  float* base = qkv + (size_t)blk * (3 * DIM);
  const float c  = cosb[s * HD + 2 * lane];   // cos[:, ::2]
  const float sn = sinb[s * HD + 2 * lane];
  #pragma unroll
  for (int h = wave; h < NH; h += 4) {
    float2* qp = (float2*)(base + h * HD + 2 * lane);
    float2* kp = (float2*)(base + DIM + h * HD + 2 * lane);
    float2 q = *qp, k = *kp;
    float ssq = q.x * q.x + q.y * q.y;
    float ssk = k.x * k.x + k.y * k.y;
    #pragma unroll
    for (int off = 32; off >= 1; off >>= 1) {
      ssq += __shfl_xor(ssq, off, 64);
      ssk += __shfl_xor(ssk, off, 64);
    }
    float rq = rsqrtf(ssq * (1.0f / HD) + EPS);
    float rk = rsqrtf(ssk * (1.0f / HD) + EPS);
    float q1 = q.x * rq, q2 = q.y * rq;
    float k1 = k.x * rk, k2 = k.y * rk;
    *qp = make_float2(q1 * c - q2 * sn, q1 * sn + q2 * c);
    *kp = make_float2(k1 * c - k2 * sn, k1 * sn + k2 * c);
  }
}

// ---------------------------------------------------------------------------
// Flash attention, fp32, online softmax.  Reads Q/K/V directly from the
// (rope'd-in-place) qkv buffer with row stride 6144 floats.  Writes O as
// SPLIT bf16 (hi/lo) ready for the out-projection GEMM.
// XOR-swizzled LDS tiles; P-tile aliases K-tile; 64 KB LDS total.
// ---------------------------------------------------------------------------
__device__ __forceinline__ int sw128(int row, int c4) {
  return (row << 5) + (c4 ^ (row & 7));
}

#define QKV_ROW4 1536   // 6144 floats / 4

__global__ __launch_bounds__(256) void flash_attn(
    const float* __restrict__ qkv, unsigned short* __restrict__ Oh,
    unsigned short* __restrict__ Ol) {
  __shared__ float4 Qs4[64 * 32];   // 32 KB
  __shared__ float4 Ks4[32 * 32];   // 16 KB (P-tile aliases)
  __shared__ float4 Vs4[32 * 32];   // 16 KB
  float* Ps = (float*)Ks4;          // [64][36] floats

  const int t = threadIdx.x;
  const int tx = t & 15, ty = t >> 4;
  const int q0 = blockIdx.x * 64;
  const float* base = qkv + (size_t)(blockIdx.z * SEQ) * (3 * DIM) + blockIdx.y * HD;
  const float4* Qg = (const float4*)base;             // row r -> r*1536 + c4
  const float4* Kg = (const float4*)(base + DIM);
  const float4* Vg = (const float4*)(base + 2 * DIM);

  #pragma unroll
  for (int l = 0; l < 8; ++l) {
    int f = t + l * 256;
    int r = f >> 5, c4 = f & 31;
    Qs4[sw128(r, c4)] = Qg[(size_t)(q0 + r) * QKV_ROW4 + c4];
  }

  float m[4], lsum[4], acc[4][8];
  #pragma unroll
  for (int i = 0; i < 4; ++i) {
    m[i] = -INFINITY; lsum[i] = 0.f;
    #pragma unroll
    for (int dd = 0; dd < 8; ++dd) acc[i][dd] = 0.f;
  }
  const float scale = 0.08838834764831845f;  // 1/sqrt(128)

  for (int kk = 0; kk < SEQ; kk += 32) {
    __syncthreads();
    #pragma unroll
    for (int l = 0; l < 4; ++l) {
      int f = t + l * 256;
      int r = f >> 5, c4 = f & 31;
      Ks4[sw128(r, c4)] = Kg[(size_t)(kk + r) * QKV_ROW4 + c4];
      Vs4[sw128(r, c4)] = Vg[(size_t)(kk + r) * QKV_ROW4 + c4];
    }
    __syncthreads();

    float sc[4][2] = {};
    #pragma unroll
    for (int d4 = 0; d4 < 32; ++d4) {
      float4 a[4], bb[2];
      #pragma unroll
      for (int i = 0; i < 4; ++i) a[i] = Qs4[sw128(ty + 16 * i, d4)];
      #pragma unroll
      for (int j = 0; j < 2; ++j) bb[j] = Ks4[sw128(tx + 16 * j, d4)];
      #pragma unroll
      for (int i = 0; i < 4; ++i)
        #pragma unroll
        for (int j = 0; j < 2; ++j)
          sc[i][j] += a[i].x * bb[j].x + a[i].y * bb[j].y +
                      a[i].z * bb[j].z + a[i].w * bb[j].w;
    }
    __syncthreads();  // done reading Ks (P aliases it)

    #pragma unroll
    for (int i = 0; i < 4; ++i) {
      float s0 = sc[i][0] * scale, s1 = sc[i][1] * scale;
      float mx = fmaxf(s0, s1);
      #pragma unroll
      for (int off = 8; off >= 1; off >>= 1) mx = fmaxf(mx, __shfl_xor(mx, off, 16));
      float mn = fmaxf(m[i], mx);
      float al = __expf(m[i] - mn);
      float p0 = __expf(s0 - mn), p1 = __expf(s1 - mn);
      float rs = p0 + p1;
      #pragma unroll
      for (int off = 8; off >= 1; off >>= 1) rs += __shfl_xor(rs, off, 16);
      lsum[i] = lsum[i] * al + rs;
      m[i] = mn;
      Ps[(ty + 16 * i) * 36 + tx]      = p0;
      Ps[(ty + 16 * i) * 36 + tx + 16] = p1;
      #pragma unroll
      for (int dd = 0; dd < 8; ++dd) acc[i][dd] *= al;
    }
    __syncthreads();

    const float* Vsf = (const float*)Vs4;
    #pragma unroll 4
    for (int k = 0; k < 32; ++k) {
      float vv[8];
      #pragma unroll
      for (int dd = 0; dd < 8; ++dd) {
        int cc = tx + 16 * dd;
        vv[dd] = Vsf[sw128(k, cc >> 2) * 4 + (cc & 3)];
      }
      #pragma unroll
      for (int i = 0; i < 4; ++i) {
        float pk = Ps[(ty + 16 * i) * 36 + k];
        #pragma unroll
        for (int dd = 0; dd < 8; ++dd) acc[i][dd] += pk * vv[dd];
      }
    }
  }

  // epilogue: O[b,s,h*128+d] as split bf16 (A-matrix of the out-projection)
  #pragma unroll
  for (int i = 0; i < 4; ++i) {
    float inv = 1.0f / lsum[i];
    int row = q0 + ty + 16 * i;
    size_t ob = ((size_t)(blockIdx.z * SEQ + row)) * DIM + blockIdx.y * HD;
    #pragma unroll
    for (int dd = 0; dd < 8; ++dd) {
      float val = acc[i][dd] * inv;
      unsigned short h = f2bf(val);
      Oh[ob + tx + 16 * dd] = h;
      Ol[ob + tx + 16 * dd] = f2bf(val - bf2f(h));
    }
  }
}

// ---------------------------------------------------------------------------
// Launch.  Workspace (184.5 MB):
//   qkv fp32 : 100,663,296 B   (gemm1 out; rope'd in place; flash reads it)
//   xh,xl    : 16,777,216 B x2 (x split; REUSED as O split after gemm1)
//   Wh,Wl    : 25,165,824 B x2 (W_qkv split; REUSED for W_proj split)
// ---------------------------------------------------------------------------
extern "C" void kernel_launch(void* const* d_in, const int* in_sizes, int n_in,
                              void* d_out, int out_size, void* d_ws, size_t ws_size,
                              hipStream_t stream) {
  const float* x     = (const float*)d_in[0];
  const float* cosb  = (const float*)d_in[1];
  const float* sinb  = (const float*)d_in[2];
  const float* Wqkv  = (const float*)d_in[3];
  const float* Wproj = (const float*)d_in[4];
  float* out = (float*)d_out;

  char* ws = (char*)d_ws;
  float* qkv          = (float*)ws;
  unsigned short* xh  = (unsigned short*)(ws + 100663296);
  unsigned short* xl  = (unsigned short*)(ws + 117440512);
  unsigned short* Wh  = (unsigned short*)(ws + 134217728);
  unsigned short* Wl  = (unsigned short*)(ws + 159383552);

  // 1) split inputs to bf16 hi/lo
  split_bf16<<<8192,  256, 0, stream>>>(x,    xh, xl);   // 8.4M floats
  split_bf16<<<12288, 256, 0, stream>>>(Wqkv, Wh, Wl);   // 12.6M floats
  // 2) qkv = x @ W_qkv^T  [4096 x 6144] fp32 out
  gemm_split<<<dim3(48, 32), 256, 0, stream>>>(xh, xl, Wh, Wl, qkv, 4096, 6144, 2048);
  // 3) RMSNorm + RoPE in place on q,k
  rmsrope_ip<<<4096, 256, 0, stream>>>(qkv, cosb, sinb);
  // 4) W_proj split (reuses Wh/Wl after gemm1 consumed them)
  split_bf16<<<4096, 256, 0, stream>>>(Wproj, Wh, Wl);
  // 5) flash attention -> O split bf16 (reuses xh/xl)
  flash_attn<<<dim3(SEQ / 64, NH, BATCH), 256, 0, stream>>>(qkv, xh, xl);
  // 6) out = O @ W_proj^T  [4096 x 2048]
  gemm_split<<<dim3(16, 32), 256, 0, stream>>>(xh, xl, Wh, Wl, out, 4096, 2048, 2048);
}

// Round 3
// 859.331 us; speedup vs baseline: 4.5861x; 2.3240x over previous
//
#include <hip/hip_runtime.h>
#include <math.h>

// Problem constants
#define BATCH 2
#define SEQ   2048
#define DIM   2048
#define NH    16
#define HD    128
#define EPS   1e-6f

typedef __bf16 bf16x8 __attribute__((ext_vector_type(8)));
typedef float  f32x4  __attribute__((ext_vector_type(4)));

// bf16 round-to-nearest-even split helpers
__device__ __forceinline__ unsigned short f2bf(float f) {
  union { float f; unsigned u; } v; v.f = f;
  unsigned r = v.u + 0x7FFFu + ((v.u >> 16) & 1u);
  return (unsigned short)(r >> 16);
}
__device__ __forceinline__ float bf2f(unsigned short h) {
  union { unsigned u; float f; } v; v.u = ((unsigned)h) << 16;
  return v.f;
}

// ---------------------------------------------------------------------------
// split fp32 -> (hi, lo) bf16
// ---------------------------------------------------------------------------
__global__ __launch_bounds__(256) void split_bf16(
    const float* __restrict__ in, unsigned short* __restrict__ hi,
    unsigned short* __restrict__ lo) {
  int i = blockIdx.x * 256 + threadIdx.x;
  float4 v = ((const float4*)in)[i];
  ushort4 h, l;
  h.x = f2bf(v.x); l.x = f2bf(v.x - bf2f(h.x));
  h.y = f2bf(v.y); l.y = f2bf(v.y - bf2f(h.y));
  h.z = f2bf(v.z); l.z = f2bf(v.z - bf2f(h.z));
  h.w = f2bf(v.w); l.w = f2bf(v.w - bf2f(h.w));
  ((ushort4*)hi)[i] = h;
  ((ushort4*)lo)[i] = l;
}

// ---------------------------------------------------------------------------
// Split-bf16 MFMA GEMM (unchanged from round 2; verified)
// ---------------------------------------------------------------------------
#define BM 128
#define BN 128
#define BK 32

__global__ __launch_bounds__(256) void gemm_split(
    const unsigned short* __restrict__ Ahg, const unsigned short* __restrict__ Alg,
    const unsigned short* __restrict__ Bhg, const unsigned short* __restrict__ Blg,
    float* __restrict__ C, int M, int N, int K) {
  __shared__ __align__(16) unsigned short Ah[BM * BK];
  __shared__ __align__(16) unsigned short Al[BM * BK];
  __shared__ __align__(16) unsigned short Bh[BM * BK];
  __shared__ __align__(16) unsigned short Bl[BM * BK];

  const int t = threadIdx.x;
  const int w = t >> 6, lane = t & 63;
  const int bm = blockIdx.y * BM, bn = blockIdx.x * BN;
  const int wr = (w >> 1) * 64, wc = (w & 1) * 64;
  const int r16 = lane & 15, kg = lane >> 4;

  const unsigned short* gsrc;
  unsigned short* lbase;
  if (w == 0)      { gsrc = Ahg + (size_t)bm * K; lbase = Ah; }
  else if (w == 1) { gsrc = Alg + (size_t)bm * K; lbase = Al; }
  else if (w == 2) { gsrc = Bhg + (size_t)bn * K; lbase = Bh; }
  else             { gsrc = Blg + (size_t)bn * K; lbase = Bl; }
  const int srow = lane >> 2, scol = (lane & 3) << 3;

  f32x4 acc[4][4] = {};

  for (int k0 = 0; k0 < K; k0 += BK) {
    __syncthreads();
    #pragma unroll
    for (int p = 0; p < 8; ++p) {
      const unsigned short* ga = gsrc + (size_t)(p * 16 + srow) * K + k0 + scol;
      __builtin_amdgcn_global_load_lds(
          (const __attribute__((address_space(1))) unsigned int*)ga,
          (__attribute__((address_space(3))) unsigned int*)(lbase + p * 512),
          16, 0, 0);
    }
    __syncthreads();

    bf16x8 ah[4], al[4], bh[4], bl[4];
    #pragma unroll
    for (int i = 0; i < 4; ++i) {
      ah[i] = *(const bf16x8*)(Ah + (wr + 16 * i + r16) * BK + kg * 8);
      al[i] = *(const bf16x8*)(Al + (wr + 16 * i + r16) * BK + kg * 8);
      bh[i] = *(const bf16x8*)(Bh + (wc + 16 * i + r16) * BK + kg * 8);
      bl[i] = *(const bf16x8*)(Bl + (wc + 16 * i + r16) * BK + kg * 8);
    }
    #pragma unroll
    for (int i = 0; i < 4; ++i)
      #pragma unroll
      for (int j = 0; j < 4; ++j)
        acc[i][j] = __builtin_amdgcn_mfma_f32_16x16x32_bf16(ah[i], bh[j], acc[i][j], 0, 0, 0);
    #pragma unroll
    for (int i = 0; i < 4; ++i)
      #pragma unroll
      for (int j = 0; j < 4; ++j)
        acc[i][j] = __builtin_amdgcn_mfma_f32_16x16x32_bf16(ah[i], bl[j], acc[i][j], 0, 0, 0);
    #pragma unroll
    for (int i = 0; i < 4; ++i)
      #pragma unroll
      for (int j = 0; j < 4; ++j)
        acc[i][j] = __builtin_amdgcn_mfma_f32_16x16x32_bf16(al[i], bh[j], acc[i][j], 0, 0, 0);
  }

  #pragma unroll
  for (int i = 0; i < 4; ++i)
    #pragma unroll
    for (int j = 0; j < 4; ++j) {
      int col = bn + wc + 16 * j + r16;
      #pragma unroll
      for (int r = 0; r < 4; ++r) {
        int row = bm + wr + 16 * i + kg * 4 + r;
        C[(size_t)row * N + col] = acc[i][j][r];
      }
    }
}

// ---------------------------------------------------------------------------
// RMSNorm + RoPE on q,k of qkv[b,s,6144]; emits split-bf16 Q,K [b,h,s,d].
// ---------------------------------------------------------------------------
__global__ __launch_bounds__(256) void rmsrope_split(
    const float* __restrict__ qkv, const float* __restrict__ cosb,
    const float* __restrict__ sinb, unsigned short* __restrict__ Qh,
    unsigned short* __restrict__ Ql, unsigned short* __restrict__ Kh,
    unsigned short* __restrict__ Kl) {
  const int blk = blockIdx.x;           // b*SEQ + s
  const int b = blk >> 11, s = blk & (SEQ - 1);
  const int wave = threadIdx.x >> 6, lane = threadIdx.x & 63;
  const float* base = qkv + (size_t)blk * (3 * DIM);
  const float c  = cosb[s * HD + 2 * lane];
  const float sn = sinb[s * HD + 2 * lane];
  #pragma unroll
  for (int h = wave; h < NH; h += 4) {
    float2 q = *(const float2*)(base + h * HD + 2 * lane);
    float2 k = *(const float2*)(base + DIM + h * HD + 2 * lane);
    float ssq = q.x * q.x + q.y * q.y;
    float ssk = k.x * k.x + k.y * k.y;
    #pragma unroll
    for (int off = 32; off >= 1; off >>= 1) {
      ssq += __shfl_xor(ssq, off, 64);
      ssk += __shfl_xor(ssk, off, 64);
    }
    float rq = rsqrtf(ssq * (1.0f / HD) + EPS);
    float rk = rsqrtf(ssk * (1.0f / HD) + EPS);
    float q1 = q.x * rq, q2 = q.y * rq;
    float k1 = k.x * rk, k2 = k.y * rk;
    float qy1 = q1 * c - q2 * sn, qy2 = q1 * sn + q2 * c;
    float ky1 = k1 * c - k2 * sn, ky2 = k1 * sn + k2 * c;
    size_t o = ((size_t)(b * NH + h) * SEQ + s) * HD + 2 * lane;
    ushort2 qh2, ql2, kh2, kl2;
    qh2.x = f2bf(qy1); ql2.x = f2bf(qy1 - bf2f(qh2.x));
    qh2.y = f2bf(qy2); ql2.y = f2bf(qy2 - bf2f(qh2.y));
    kh2.x = f2bf(ky1); kl2.x = f2bf(ky1 - bf2f(kh2.x));
    kh2.y = f2bf(ky2); kl2.y = f2bf(ky2 - bf2f(kh2.y));
    *(ushort2*)(Qh + o) = qh2;
    *(ushort2*)(Ql + o) = ql2;
    *(ushort2*)(Kh + o) = kh2;
    *(ushort2*)(Kl + o) = kl2;
  }
}

// ---------------------------------------------------------------------------
// V transpose+split: qkv v-slice [64 s][128 d] fp32 -> Vt [b,h,d,s] bf16 hi/lo.
// LDS stride 132 (66 words, even->8B aligned writes; col reads 2-way only).
// ---------------------------------------------------------------------------
__global__ __launch_bounds__(256) void vtrans(
    const float* __restrict__ qkv, unsigned short* __restrict__ Vth,
    unsigned short* __restrict__ Vtl) {
  __shared__ unsigned short Lh[64 * 132];
  __shared__ unsigned short Ll[64 * 132];
  const int t = threadIdx.x;
  const int s0 = blockIdx.x * 64, h = blockIdx.y, b = blockIdx.z;
  const float* src = qkv + ((size_t)(b * SEQ + s0)) * (3 * DIM) + 2 * DIM + h * HD;
  #pragma unroll
  for (int it = 0; it < 8; ++it) {
    int f = t + it * 256;
    int r = f >> 5, c4 = f & 31;
    float4 v = *(const float4*)(src + (size_t)r * (3 * DIM) + c4 * 4);
    ushort4 hh, ll;
    hh.x = f2bf(v.x); ll.x = f2bf(v.x - bf2f(hh.x));
    hh.y = f2bf(v.y); ll.y = f2bf(v.y - bf2f(hh.y));
    hh.z = f2bf(v.z); ll.z = f2bf(v.z - bf2f(hh.z));
    hh.w = f2bf(v.w); ll.w = f2bf(v.w - bf2f(hh.w));
    *(ushort4*)(&Lh[r * 132 + c4 * 4]) = hh;
    *(ushort4*)(&Ll[r * 132 + c4 * 4]) = ll;
  }
  __syncthreads();
  const int d = t >> 1, sc = (t & 1) * 32;
  size_t dst = ((size_t)((b * NH + h) * HD + d)) * SEQ + s0 + sc;
  #pragma unroll
  for (int j = 0; j < 8; ++j) {
    ushort4 oh, ol;
    oh.x = Lh[(sc + 4 * j + 0) * 132 + d]; ol.x = Ll[(sc + 4 * j + 0) * 132 + d];
    oh.y = Lh[(sc + 4 * j + 1) * 132 + d]; ol.y = Ll[(sc + 4 * j + 1) * 132 + d];
    oh.z = Lh[(sc + 4 * j + 2) * 132 + d]; ol.z = Ll[(sc + 4 * j + 2) * 132 + d];
    oh.w = Lh[(sc + 4 * j + 3) * 132 + d]; ol.w = Ll[(sc + 4 * j + 3) * 132 + d];
    *(ushort4*)(Vth + dst + j * 4) = oh;
    *(ushort4*)(Vtl + dst + j * 4) = ol;
  }
}

// ---------------------------------------------------------------------------
// MFMA flash attention.  Block = 128 Q-rows (4 waves x 32 rows), KC=32.
// QK^T: 3-pass split bf16.  PV: P bf16 x (Vh + Vl).
// All tiles staged via global_load_lds with XOR-swizzled chunk placement
// (swizzle realized on the global source address; LDS dest lane-contiguous).
// P round-trips through per-wave LDS [32][40] (pad -> conflict-free b128).
// LDS total 42 KB.
// ---------------------------------------------------------------------------
#define QT 128
#define KC 32
#define MFMA_B16 __builtin_amdgcn_mfma_f32_16x16x32_bf16

__global__ __launch_bounds__(256, 2) void flash_mfma(
    const unsigned short* __restrict__ Qh_g, const unsigned short* __restrict__ Ql_g,
    const unsigned short* __restrict__ Kh_g, const unsigned short* __restrict__ Kl_g,
    const unsigned short* __restrict__ Vth_g, const unsigned short* __restrict__ Vtl_g,
    unsigned short* __restrict__ Oh_g, unsigned short* __restrict__ Ol_g) {
  // [0,4096): Kh  [4096,8192): Kl  [8192,12288): Vth  [12288,16384): Vtl
  // [16384,21504): P, per wave [32][40].  Q staging reuses [0,16384).
  __shared__ __align__(16) unsigned short sm[21504];

  const int t = threadIdx.x, w = t >> 6, lane = t & 63;
  const int quad = lane >> 4, c15 = lane & 15;
  const int hy = blockIdx.y, bz = blockIdx.z;
  const int bh = bz * NH + hy;
  const int q0 = blockIdx.x * QT;
  const int wr = w * 32;

  // ---- load Q fragments (hi then lo) through LDS into registers ----
  bf16x8 qf[2][2][4];  // [hi/lo][mf][ks]
  const unsigned short* qsrcs[2] = {Qh_g, Ql_g};
  #pragma unroll
  for (int pass = 0; pass < 2; ++pass) {
    __syncthreads();
    const unsigned short* qsrc = qsrcs[pass] + ((size_t)bh * SEQ + q0) * HD;
    #pragma unroll
    for (int p = 0; p < 8; ++p) {
      int ci = p * 256 + t;
      int r = ci >> 4, c8 = (ci & 15) ^ (r & 15);
      __builtin_amdgcn_global_load_lds(
          (const __attribute__((address_space(1))) unsigned int*)(qsrc + (size_t)r * HD + c8 * 8),
          (__attribute__((address_space(3))) unsigned int*)(sm + ci * 8), 16, 0, 0);
    }
    __syncthreads();
    #pragma unroll
    for (int mf = 0; mf < 2; ++mf)
      #pragma unroll
      for (int ks = 0; ks < 4; ++ks) {
        int m = wr + mf * 16 + c15;
        int c8 = ks * 4 + quad;
        qf[pass][mf][ks] = *(const bf16x8*)(sm + (m * 16 + (c8 ^ (m & 15))) * 8);
      }
  }

  float mrow[8], lrow[8];
  f32x4 oacc[2][8];
  #pragma unroll
  for (int i = 0; i < 8; ++i) { mrow[i] = -INFINITY; lrow[i] = 0.f; }
  #pragma unroll
  for (int mf = 0; mf < 2; ++mf)
    #pragma unroll
    for (int nf = 0; nf < 8; ++nf) oacc[mf][nf] = (f32x4){0.f, 0.f, 0.f, 0.f};

  const float scale = 0.08838834764831845f;  // 1/sqrt(128)
  unsigned short* Pw = sm + 16384 + w * 1280;

  for (int kk = 0; kk < SEQ; kk += KC) {
    __syncthreads();  // all waves done with previous K/V tiles
    if (w < 2) {      // K tiles [32][128]
      const unsigned short* src = (w == 0 ? Kh_g : Kl_g) + ((size_t)bh * SEQ + kk) * HD;
      #pragma unroll
      for (int p = 0; p < 8; ++p) {
        int ci = p * 64 + lane;
        int r = ci >> 4, c8 = (ci & 15) ^ (r & 15);
        __builtin_amdgcn_global_load_lds(
            (const __attribute__((address_space(1))) unsigned int*)(src + (size_t)r * HD + c8 * 8),
            (__attribute__((address_space(3))) unsigned int*)(sm + w * 4096 + ci * 8), 16, 0, 0);
      }
    } else {          // V^T tiles [128][32]
      const unsigned short* src = (w == 2 ? Vth_g : Vtl_g) + (size_t)bh * HD * SEQ + kk;
      #pragma unroll
      for (int p = 0; p < 8; ++p) {
        int ci = p * 64 + lane;
        int d = ci >> 2, c8 = (ci & 3) ^ (d & 3);
        __builtin_amdgcn_global_load_lds(
            (const __attribute__((address_space(1))) unsigned int*)(src + (size_t)d * SEQ + c8 * 8),
            (__attribute__((address_space(3))) unsigned int*)(sm + w * 4096 + ci * 8), 16, 0, 0);
      }
    }
    __syncthreads();

    // ---- S = Q K^T (3-pass split) ----
    f32x4 accs[2][2] = {};
    #pragma unroll
    for (int nf = 0; nf < 2; ++nf) {
      bf16x8 kh[4], kl[4];
      #pragma unroll
      for (int ks = 0; ks < 4; ++ks) {
        int n = nf * 16 + c15;
        int c8 = ks * 4 + quad;
        int slot = (n * 16 + (c8 ^ (n & 15))) * 8;
        kh[ks] = *(const bf16x8*)(sm + slot);
        kl[ks] = *(const bf16x8*)(sm + 4096 + slot);
      }
      #pragma unroll
      for (int ks = 0; ks < 4; ++ks) {
        accs[0][nf] = MFMA_B16(qf[0][0][ks], kh[ks], accs[0][nf], 0, 0, 0);
        accs[1][nf] = MFMA_B16(qf[0][1][ks], kh[ks], accs[1][nf], 0, 0, 0);
      }
      #pragma unroll
      for (int ks = 0; ks < 4; ++ks) {
        accs[0][nf] = MFMA_B16(qf[0][0][ks], kl[ks], accs[0][nf], 0, 0, 0);
        accs[1][nf] = MFMA_B16(qf[0][1][ks], kl[ks], accs[1][nf], 0, 0, 0);
        accs[0][nf] = MFMA_B16(qf[1][0][ks], kh[ks], accs[0][nf], 0, 0, 0);
        accs[1][nf] = MFMA_B16(qf[1][1][ks], kh[ks], accs[1][nf], 0, 0, 0);
      }
    }

    // ---- online softmax (rows live in C/D layout: row = quad*4+reg) ----
    #pragma unroll
    for (int mf = 0; mf < 2; ++mf)
      #pragma unroll
      for (int reg = 0; reg < 4; ++reg) {
        int idx = mf * 4 + reg;
        float v0 = accs[mf][0][reg] * scale;
        float v1 = accs[mf][1][reg] * scale;
        float mx = fmaxf(v0, v1);
        #pragma unroll
        for (int off = 8; off >= 1; off >>= 1) mx = fmaxf(mx, __shfl_xor(mx, off, 64));
        float mn = fmaxf(mrow[idx], mx);
        float al = __expf(mrow[idx] - mn);
        float p0 = __expf(v0 - mn), p1 = __expf(v1 - mn);
        float rs = p0 + p1;
        #pragma unroll
        for (int off = 8; off >= 1; off >>= 1) rs += __shfl_xor(rs, off, 64);
        lrow[idx] = lrow[idx] * al + rs;
        mrow[idx] = mn;
        int prow = mf * 16 + quad * 4 + reg;
        Pw[prow * 40 + c15]      = f2bf(p0);
        Pw[prow * 40 + c15 + 16] = f2bf(p1);
        #pragma unroll
        for (int nf = 0; nf < 8; ++nf) oacc[mf][nf][reg] *= al;
      }
    // (within-wave P write->read: compiler inserts lgkmcnt wait; no barrier)

    // ---- O += P V ----
    bf16x8 pa0 = *(const bf16x8*)(Pw + (c15) * 40 + quad * 8);
    bf16x8 pa1 = *(const bf16x8*)(Pw + (16 + c15) * 40 + quad * 8);
    #pragma unroll
    for (int nf = 0; nf < 8; ++nf) {
      int dd = nf * 16 + c15;
      int slot = (dd * 4 + (quad ^ (dd & 3))) * 8;
      bf16x8 vh = *(const bf16x8*)(sm + 8192 + slot);
      bf16x8 vl = *(const bf16x8*)(sm + 12288 + slot);
      oacc[0][nf] = MFMA_B16(pa0, vh, oacc[0][nf], 0, 0, 0);
      oacc[0][nf] = MFMA_B16(pa0, vl, oacc[0][nf], 0, 0, 0);
      oacc[1][nf] = MFMA_B16(pa1, vh, oacc[1][nf], 0, 0, 0);
      oacc[1][nf] = MFMA_B16(pa1, vl, oacc[1][nf], 0, 0, 0);
    }
  }

  // ---- epilogue: O /= l, write split bf16 [b,s,h*128+d] ----
  #pragma unroll
  for (int mf = 0; mf < 2; ++mf)
    #pragma unroll
    for (int reg = 0; reg < 4; ++reg) {
      float inv = 1.0f / lrow[mf * 4 + reg];
      int row = q0 + wr + mf * 16 + quad * 4 + reg;
      size_t ob = ((size_t)bz * SEQ + row) * DIM + hy * HD + c15;
      #pragma unroll
      for (int nf = 0; nf < 8; ++nf) {
        float val = oacc[mf][nf][reg] * inv;
        unsigned short hh = f2bf(val);
        Oh_g[ob + nf * 16] = hh;
        Ol_g[ob + nf * 16] = f2bf(val - bf2f(hh));
      }
    }
}

// ---------------------------------------------------------------------------
// Launch.  Workspace 201,326,592 B (same as round 1):
//   [0, 100663296)            qkv fp32  -> later Oh/Ol + Wproj split
//   [100663296, 201326592) R: xh/xl/Wh/Wl (pre-gemm1) -> Qh/Ql/Kh/Kl/Vth/Vtl
// ---------------------------------------------------------------------------
extern "C" void kernel_launch(void* const* d_in, const int* in_sizes, int n_in,
                              void* d_out, int out_size, void* d_ws, size_t ws_size,
                              hipStream_t stream) {
  const float* x     = (const float*)d_in[0];
  const float* cosb  = (const float*)d_in[1];
  const float* sinb  = (const float*)d_in[2];
  const float* Wqkv  = (const float*)d_in[3];
  const float* Wproj = (const float*)d_in[4];
  float* out = (float*)d_out;

  char* ws = (char*)d_ws;
  float* qkv = (float*)ws;
  char* R = ws + 100663296;
  // pre-gemm1 (dead after gemm1):
  unsigned short* xh = (unsigned short*)(R);
  unsigned short* xl = (unsigned short*)(R + 16777216);
  unsigned short* Wh = (unsigned short*)(R + 33554432);
  unsigned short* Wl = (unsigned short*)(R + 58720256);
  // post-gemm1 (aliases above):
  unsigned short* Qh  = (unsigned short*)(R);
  unsigned short* Ql  = (unsigned short*)(R + 16777216);
  unsigned short* Kh  = (unsigned short*)(R + 33554432);
  unsigned short* Kl  = (unsigned short*)(R + 50331648);
  unsigned short* Vth = (unsigned short*)(R + 67108864);
  unsigned short* Vtl = (unsigned short*)(R + 83886080);
  // post-rope/vtrans (qkv region dead):
  unsigned short* Oh  = (unsigned short*)(ws);
  unsigned short* Ol  = (unsigned short*)(ws + 16777216);
  unsigned short* Wph = (unsigned short*)(ws + 33554432);
  unsigned short* Wpl = (unsigned short*)(ws + 41943040);

  split_bf16<<<8192,  256, 0, stream>>>(x,    xh, xl);
  split_bf16<<<12288, 256, 0, stream>>>(Wqkv, Wh, Wl);
  gemm_split<<<dim3(48, 32), 256, 0, stream>>>(xh, xl, Wh, Wl, qkv, 4096, 6144, 2048);
  rmsrope_split<<<4096, 256, 0, stream>>>(qkv, cosb, sinb, Qh, Ql, Kh, Kl);
  vtrans<<<dim3(32, NH, BATCH), 256, 0, stream>>>(qkv, Vth, Vtl);
  flash_mfma<<<dim3(SEQ / QT, NH, BATCH), 256, 0, stream>>>(Qh, Ql, Kh, Kl, Vth, Vtl, Oh, Ol);
  split_bf16<<<4096, 256, 0, stream>>>(Wproj, Wph, Wpl);
  gemm_split<<<dim3(16, 32), 256, 0, stream>>>(Oh, Ol, Wph, Wpl, out, 4096, 2048, 2048);
}

// Round 4
// 723.497 us; speedup vs baseline: 5.4471x; 1.1877x over previous
//
#include <hip/hip_runtime.h>
#include <math.h>

// Problem constants
#define BATCH 2
#define SEQ   2048
#define DIM   2048
#define NH    16
#define HD    128
#define EPS   1e-6f

typedef __bf16 bf16x8 __attribute__((ext_vector_type(8)));
typedef float  f32x4  __attribute__((ext_vector_type(4)));

// bf16 round-to-nearest-even split helpers
__device__ __forceinline__ unsigned short f2bf(float f) {
  union { float f; unsigned u; } v; v.f = f;
  unsigned r = v.u + 0x7FFFu + ((v.u >> 16) & 1u);
  return (unsigned short)(r >> 16);
}
__device__ __forceinline__ float bf2f(unsigned short h) {
  union { unsigned u; float f; } v; v.u = ((unsigned)h) << 16;
  return v.f;
}

// ---------------------------------------------------------------------------
// split fp32 -> (hi, lo) bf16
// ---------------------------------------------------------------------------
__global__ __launch_bounds__(256) void split_bf16(
    const float* __restrict__ in, unsigned short* __restrict__ hi,
    unsigned short* __restrict__ lo) {
  int i = blockIdx.x * 256 + threadIdx.x;
  float4 v = ((const float4*)in)[i];
  ushort4 h, l;
  h.x = f2bf(v.x); l.x = f2bf(v.x - bf2f(h.x));
  h.y = f2bf(v.y); l.y = f2bf(v.y - bf2f(h.y));
  h.z = f2bf(v.z); l.z = f2bf(v.z - bf2f(h.z));
  h.w = f2bf(v.w); l.w = f2bf(v.w - bf2f(h.w));
  ((ushort4*)hi)[i] = h;
  ((ushort4*)lo)[i] = l;
}

// ---------------------------------------------------------------------------
// Split-bf16 MFMA GEMM (verified rounds 2-3)
// ---------------------------------------------------------------------------
#define BM 128
#define BN 128
#define BK 32

__global__ __launch_bounds__(256) void gemm_split(
    const unsigned short* __restrict__ Ahg, const unsigned short* __restrict__ Alg,
    const unsigned short* __restrict__ Bhg, const unsigned short* __restrict__ Blg,
    float* __restrict__ C, int M, int N, int K) {
  __shared__ __align__(16) unsigned short Ah[BM * BK];
  __shared__ __align__(16) unsigned short Al[BM * BK];
  __shared__ __align__(16) unsigned short Bh[BM * BK];
  __shared__ __align__(16) unsigned short Bl[BM * BK];

  const int t = threadIdx.x;
  const int w = t >> 6, lane = t & 63;
  const int bm = blockIdx.y * BM, bn = blockIdx.x * BN;
  const int wr = (w >> 1) * 64, wc = (w & 1) * 64;
  const int r16 = lane & 15, kg = lane >> 4;

  const unsigned short* gsrc;
  unsigned short* lbase;
  if (w == 0)      { gsrc = Ahg + (size_t)bm * K; lbase = Ah; }
  else if (w == 1) { gsrc = Alg + (size_t)bm * K; lbase = Al; }
  else if (w == 2) { gsrc = Bhg + (size_t)bn * K; lbase = Bh; }
  else             { gsrc = Blg + (size_t)bn * K; lbase = Bl; }
  const int srow = lane >> 2, scol = (lane & 3) << 3;

  f32x4 acc[4][4] = {};

  for (int k0 = 0; k0 < K; k0 += BK) {
    __syncthreads();
    #pragma unroll
    for (int p = 0; p < 8; ++p) {
      const unsigned short* ga = gsrc + (size_t)(p * 16 + srow) * K + k0 + scol;
      __builtin_amdgcn_global_load_lds(
          (const __attribute__((address_space(1))) unsigned int*)ga,
          (__attribute__((address_space(3))) unsigned int*)(lbase + p * 512),
          16, 0, 0);
    }
    __syncthreads();

    bf16x8 ah[4], al[4], bh[4], bl[4];
    #pragma unroll
    for (int i = 0; i < 4; ++i) {
      ah[i] = *(const bf16x8*)(Ah + (wr + 16 * i + r16) * BK + kg * 8);
      al[i] = *(const bf16x8*)(Al + (wr + 16 * i + r16) * BK + kg * 8);
      bh[i] = *(const bf16x8*)(Bh + (wc + 16 * i + r16) * BK + kg * 8);
      bl[i] = *(const bf16x8*)(Bl + (wc + 16 * i + r16) * BK + kg * 8);
    }
    #pragma unroll
    for (int i = 0; i < 4; ++i)
      #pragma unroll
      for (int j = 0; j < 4; ++j)
        acc[i][j] = __builtin_amdgcn_mfma_f32_16x16x32_bf16(ah[i], bh[j], acc[i][j], 0, 0, 0);
    #pragma unroll
    for (int i = 0; i < 4; ++i)
      #pragma unroll
      for (int j = 0; j < 4; ++j)
        acc[i][j] = __builtin_amdgcn_mfma_f32_16x16x32_bf16(ah[i], bl[j], acc[i][j], 0, 0, 0);
    #pragma unroll
    for (int i = 0; i < 4; ++i)
      #pragma unroll
      for (int j = 0; j < 4; ++j)
        acc[i][j] = __builtin_amdgcn_mfma_f32_16x16x32_bf16(al[i], bh[j], acc[i][j], 0, 0, 0);
  }

  #pragma unroll
  for (int i = 0; i < 4; ++i)
    #pragma unroll
    for (int j = 0; j < 4; ++j) {
      int col = bn + wc + 16 * j + r16;
      #pragma unroll
      for (int r = 0; r < 4; ++r) {
        int row = bm + wr + 16 * i + kg * 4 + r;
        C[(size_t)row * N + col] = acc[i][j][r];
      }
    }
}

// ---------------------------------------------------------------------------
// RMSNorm + RoPE on q,k of qkv[b,s,6144]; emits split-bf16 Q,K [b,h,s,d].
// ---------------------------------------------------------------------------
__global__ __launch_bounds__(256) void rmsrope_split(
    const float* __restrict__ qkv, const float* __restrict__ cosb,
    const float* __restrict__ sinb, unsigned short* __restrict__ Qh,
    unsigned short* __restrict__ Ql, unsigned short* __restrict__ Kh,
    unsigned short* __restrict__ Kl) {
  const int blk = blockIdx.x;           // b*SEQ + s
  const int b = blk >> 11, s = blk & (SEQ - 1);
  const int wave = threadIdx.x >> 6, lane = threadIdx.x & 63;
  const float* base = qkv + (size_t)blk * (3 * DIM);
  const float c  = cosb[s * HD + 2 * lane];
  const float sn = sinb[s * HD + 2 * lane];
  #pragma unroll
  for (int h = wave; h < NH; h += 4) {
    float2 q = *(const float2*)(base + h * HD + 2 * lane);
    float2 k = *(const float2*)(base + DIM + h * HD + 2 * lane);
    float ssq = q.x * q.x + q.y * q.y;
    float ssk = k.x * k.x + k.y * k.y;
    #pragma unroll
    for (int off = 32; off >= 1; off >>= 1) {
      ssq += __shfl_xor(ssq, off, 64);
      ssk += __shfl_xor(ssk, off, 64);
    }
    float rq = rsqrtf(ssq * (1.0f / HD) + EPS);
    float rk = rsqrtf(ssk * (1.0f / HD) + EPS);
    float q1 = q.x * rq, q2 = q.y * rq;
    float k1 = k.x * rk, k2 = k.y * rk;
    float qy1 = q1 * c - q2 * sn, qy2 = q1 * sn + q2 * c;
    float ky1 = k1 * c - k2 * sn, ky2 = k1 * sn + k2 * c;
    size_t o = ((size_t)(b * NH + h) * SEQ + s) * HD + 2 * lane;
    ushort2 qh2, ql2, kh2, kl2;
    qh2.x = f2bf(qy1); ql2.x = f2bf(qy1 - bf2f(qh2.x));
    qh2.y = f2bf(qy2); ql2.y = f2bf(qy2 - bf2f(qh2.y));
    kh2.x = f2bf(ky1); kl2.x = f2bf(ky1 - bf2f(kh2.x));
    kh2.y = f2bf(ky2); kl2.y = f2bf(ky2 - bf2f(kh2.y));
    *(ushort2*)(Qh + o) = qh2;
    *(ushort2*)(Ql + o) = ql2;
    *(ushort2*)(Kh + o) = kh2;
    *(ushort2*)(Kl + o) = kl2;
  }
}

// ---------------------------------------------------------------------------
// V transpose+split (verified round 3)
// ---------------------------------------------------------------------------
__global__ __launch_bounds__(256) void vtrans(
    const float* __restrict__ qkv, unsigned short* __restrict__ Vth,
    unsigned short* __restrict__ Vtl) {
  __shared__ unsigned short Lh[64 * 132];
  __shared__ unsigned short Ll[64 * 132];
  const int t = threadIdx.x;
  const int s0 = blockIdx.x * 64, h = blockIdx.y, b = blockIdx.z;
  const float* src = qkv + ((size_t)(b * SEQ + s0)) * (3 * DIM) + 2 * DIM + h * HD;
  #pragma unroll
  for (int it = 0; it < 8; ++it) {
    int f = t + it * 256;
    int r = f >> 5, c4 = f & 31;
    float4 v = *(const float4*)(src + (size_t)r * (3 * DIM) + c4 * 4);
    ushort4 hh, ll;
    hh.x = f2bf(v.x); ll.x = f2bf(v.x - bf2f(hh.x));
    hh.y = f2bf(v.y); ll.y = f2bf(v.y - bf2f(hh.y));
    hh.z = f2bf(v.z); ll.z = f2bf(v.z - bf2f(hh.z));
    hh.w = f2bf(v.w); ll.w = f2bf(v.w - bf2f(hh.w));
    *(ushort4*)(&Lh[r * 132 + c4 * 4]) = hh;
    *(ushort4*)(&Ll[r * 132 + c4 * 4]) = ll;
  }
  __syncthreads();
  const int d = t >> 1, sc = (t & 1) * 32;
  size_t dst = ((size_t)((b * NH + h) * HD + d)) * SEQ + s0 + sc;
  #pragma unroll
  for (int j = 0; j < 8; ++j) {
    ushort4 oh, ol;
    oh.x = Lh[(sc + 4 * j + 0) * 132 + d]; ol.x = Ll[(sc + 4 * j + 0) * 132 + d];
    oh.y = Lh[(sc + 4 * j + 1) * 132 + d]; ol.y = Ll[(sc + 4 * j + 1) * 132 + d];
    oh.z = Lh[(sc + 4 * j + 2) * 132 + d]; ol.z = Ll[(sc + 4 * j + 2) * 132 + d];
    oh.w = Lh[(sc + 4 * j + 3) * 132 + d]; ol.w = Ll[(sc + 4 * j + 3) * 132 + d];
    *(ushort4*)(Vth + dst + j * 4) = oh;
    *(ushort4*)(Vtl + dst + j * 4) = ol;
  }
}

// ---------------------------------------------------------------------------
// MFMA flash attention with FIXED-MAX softmax.
// RMSNorm + RoPE guarantee |score| <= sqrt(128) = 11.3137, so softmax uses a
// constant shift M instead of a running max: no max-reduce, no alpha rescale
// of the O accumulator, and lsum accumulates LANE-LOCALLY (single cross-lane
// reduce in the epilogue).  p = exp2(raw*scale*log2e - M*log2e).
// QK^T: 3-pass split bf16.  PV: P bf16 x (Vh + Vl).  LDS 42 KB.
// ---------------------------------------------------------------------------
#define QT 128
#define KC 32
#define MFMA_B16 __builtin_amdgcn_mfma_f32_16x16x32_bf16

__global__ __launch_bounds__(256, 2) void flash_mfma(
    const unsigned short* __restrict__ Qh_g, const unsigned short* __restrict__ Ql_g,
    const unsigned short* __restrict__ Kh_g, const unsigned short* __restrict__ Kl_g,
    const unsigned short* __restrict__ Vth_g, const unsigned short* __restrict__ Vtl_g,
    unsigned short* __restrict__ Oh_g, unsigned short* __restrict__ Ol_g) {
  // [0,4096): Kh  [4096,8192): Kl  [8192,12288): Vth  [12288,16384): Vtl
  // [16384,21504): P, per wave [32][40].  Q staging reuses [0,16384).
  __shared__ __align__(16) unsigned short sm[21504];

  const int t = threadIdx.x, w = t >> 6, lane = t & 63;
  const int quad = lane >> 4, c15 = lane & 15;
  const int hy = blockIdx.y, bz = blockIdx.z;
  const int bh = bz * NH + hy;
  const int q0 = blockIdx.x * QT;
  const int wr = w * 32;

  // ---- load Q fragments (hi then lo) through LDS into registers ----
  bf16x8 qf[2][2][4];  // [hi/lo][mf][ks]
  const unsigned short* qsrcs[2] = {Qh_g, Ql_g};
  #pragma unroll
  for (int pass = 0; pass < 2; ++pass) {
    __syncthreads();
    const unsigned short* qsrc = qsrcs[pass] + ((size_t)bh * SEQ + q0) * HD;
    #pragma unroll
    for (int p = 0; p < 8; ++p) {
      int ci = p * 256 + t;
      int r = ci >> 4, c8 = (ci & 15) ^ (r & 15);
      __builtin_amdgcn_global_load_lds(
          (const __attribute__((address_space(1))) unsigned int*)(qsrc + (size_t)r * HD + c8 * 8),
          (__attribute__((address_space(3))) unsigned int*)(sm + ci * 8), 16, 0, 0);
    }
    __syncthreads();
    #pragma unroll
    for (int mf = 0; mf < 2; ++mf)
      #pragma unroll
      for (int ks = 0; ks < 4; ++ks) {
        int m = wr + mf * 16 + c15;
        int c8 = ks * 4 + quad;
        qf[pass][mf][ks] = *(const bf16x8*)(sm + (m * 16 + (c8 ^ (m & 15))) * 8);
      }
  }

  float lrow[8];                      // lane-local partial softmax denominators
  f32x4 oacc[2][8];
  #pragma unroll
  for (int i = 0; i < 8; ++i) lrow[i] = 0.f;
  #pragma unroll
  for (int mf = 0; mf < 2; ++mf)
    #pragma unroll
    for (int nf = 0; nf < 8; ++nf) oacc[mf][nf] = (f32x4){0.f, 0.f, 0.f, 0.f};

  // scale*log2e and fixed max in exp2 domain:
  // scale = 1/sqrt(128); M = sqrt(128);  M2 = M*scale*... = 128/sqrt(128)*scale
  const float sl = 0.12751744f;       // (1/sqrt(128)) * log2(e)
  const float M2 = 16.322231f;        // sqrt(128) * log2(e)
  unsigned short* Pw = sm + 16384 + w * 1280;

  for (int kk = 0; kk < SEQ; kk += KC) {
    __syncthreads();  // all waves done with previous K/V tiles
    if (w < 2) {      // K tiles [32][128]
      const unsigned short* src = (w == 0 ? Kh_g : Kl_g) + ((size_t)bh * SEQ + kk) * HD;
      #pragma unroll
      for (int p = 0; p < 8; ++p) {
        int ci = p * 64 + lane;
        int r = ci >> 4, c8 = (ci & 15) ^ (r & 15);
        __builtin_amdgcn_global_load_lds(
            (const __attribute__((address_space(1))) unsigned int*)(src + (size_t)r * HD + c8 * 8),
            (__attribute__((address_space(3))) unsigned int*)(sm + w * 4096 + ci * 8), 16, 0, 0);
      }
    } else {          // V^T tiles [128][32]
      const unsigned short* src = (w == 2 ? Vth_g : Vtl_g) + (size_t)bh * HD * SEQ + kk;
      #pragma unroll
      for (int p = 0; p < 8; ++p) {
        int ci = p * 64 + lane;
        int d = ci >> 2, c8 = (ci & 3) ^ (d & 3);
        __builtin_amdgcn_global_load_lds(
            (const __attribute__((address_space(1))) unsigned int*)(src + (size_t)d * SEQ + c8 * 8),
            (__attribute__((address_space(3))) unsigned int*)(sm + w * 4096 + ci * 8), 16, 0, 0);
      }
    }
    __syncthreads();

    // ---- S = Q K^T (3-pass split) ----
    f32x4 accs[2][2] = {};
    #pragma unroll
    for (int nf = 0; nf < 2; ++nf) {
      bf16x8 kh[4], kl[4];
      #pragma unroll
      for (int ks = 0; ks < 4; ++ks) {
        int n = nf * 16 + c15;
        int c8 = ks * 4 + quad;
        int slot = (n * 16 + (c8 ^ (n & 15))) * 8;
        kh[ks] = *(const bf16x8*)(sm + slot);
        kl[ks] = *(const bf16x8*)(sm + 4096 + slot);
      }
      #pragma unroll
      for (int ks = 0; ks < 4; ++ks) {
        accs[0][nf] = MFMA_B16(qf[0][0][ks], kh[ks], accs[0][nf], 0, 0, 0);
        accs[1][nf] = MFMA_B16(qf[0][1][ks], kh[ks], accs[1][nf], 0, 0, 0);
      }
      #pragma unroll
      for (int ks = 0; ks < 4; ++ks) {
        accs[0][nf] = MFMA_B16(qf[1][0][ks], kh[ks], accs[0][nf], 0, 0, 0);
        accs[1][nf] = MFMA_B16(qf[1][1][ks], kh[ks], accs[1][nf], 0, 0, 0);
        accs[0][nf] = MFMA_B16(qf[0][0][ks], kl[ks], accs[0][nf], 0, 0, 0);
        accs[1][nf] = MFMA_B16(qf[0][1][ks], kl[ks], accs[1][nf], 0, 0, 0);
      }
    }

    // ---- softmax weights with fixed shift (no reductions, no rescale) ----
    #pragma unroll
    for (int mf = 0; mf < 2; ++mf)
      #pragma unroll
      for (int reg = 0; reg < 4; ++reg) {
        float p0 = exp2f(fmaf(accs[mf][0][reg], sl, -M2));
        float p1 = exp2f(fmaf(accs[mf][1][reg], sl, -M2));
        lrow[mf * 4 + reg] += p0 + p1;
        int prow = mf * 16 + quad * 4 + reg;
        Pw[prow * 40 + c15]      = f2bf(p0);
        Pw[prow * 40 + c15 + 16] = f2bf(p1);
      }
    // (within-wave P write->read: compiler inserts lgkmcnt wait; no barrier)

    // ---- O += P V ----
    bf16x8 pa0 = *(const bf16x8*)(Pw + (c15) * 40 + quad * 8);
    bf16x8 pa1 = *(const bf16x8*)(Pw + (16 + c15) * 40 + quad * 8);
    #pragma unroll
    for (int nf = 0; nf < 8; ++nf) {
      int dd = nf * 16 + c15;
      int slot = (dd * 4 + (quad ^ (dd & 3))) * 8;
      bf16x8 vh = *(const bf16x8*)(sm + 8192 + slot);
      bf16x8 vl = *(const bf16x8*)(sm + 12288 + slot);
      oacc[0][nf] = MFMA_B16(pa0, vh, oacc[0][nf], 0, 0, 0);
      oacc[0][nf] = MFMA_B16(pa0, vl, oacc[0][nf], 0, 0, 0);
      oacc[1][nf] = MFMA_B16(pa1, vh, oacc[1][nf], 0, 0, 0);
      oacc[1][nf] = MFMA_B16(pa1, vl, oacc[1][nf], 0, 0, 0);
    }
  }

  // ---- epilogue: reduce lsum across the 16 lanes of each quad-row group ----
  #pragma unroll
  for (int i = 0; i < 8; ++i) {
    float s = lrow[i];
    #pragma unroll
    for (int off = 8; off >= 1; off >>= 1) s += __shfl_xor(s, off, 64);
    lrow[i] = s;
  }
  #pragma unroll
  for (int mf = 0; mf < 2; ++mf)
    #pragma unroll
    for (int reg = 0; reg < 4; ++reg) {
      float inv = 1.0f / lrow[mf * 4 + reg];
      int row = q0 + wr + mf * 16 + quad * 4 + reg;
      size_t ob = ((size_t)bz * SEQ + row) * DIM + hy * HD + c15;
      #pragma unroll
      for (int nf = 0; nf < 8; ++nf) {
        float val = oacc[mf][nf][reg] * inv;
        unsigned short hh = f2bf(val);
        Oh_g[ob + nf * 16] = hh;
        Ol_g[ob + nf * 16] = f2bf(val - bf2f(hh));
      }
    }
}

// ---------------------------------------------------------------------------
// Launch.  Workspace 201,326,592 B:
//   [0, 100663296)            qkv fp32  -> later Oh/Ol + Wproj split
//   [100663296, 201326592) R: xh/xl/Wh/Wl (pre-gemm1) -> Qh/Ql/Kh/Kl/Vth/Vtl
// ---------------------------------------------------------------------------
extern "C" void kernel_launch(void* const* d_in, const int* in_sizes, int n_in,
                              void* d_out, int out_size, void* d_ws, size_t ws_size,
                              hipStream_t stream) {
  const float* x     = (const float*)d_in[0];
  const float* cosb  = (const float*)d_in[1];
  const float* sinb  = (const float*)d_in[2];
  const float* Wqkv  = (const float*)d_in[3];
  const float* Wproj = (const float*)d_in[4];
  float* out = (float*)d_out;

  char* ws = (char*)d_ws;
  float* qkv = (float*)ws;
  char* R = ws + 100663296;
  unsigned short* xh = (unsigned short*)(R);
  unsigned short* xl = (unsigned short*)(R + 16777216);
  unsigned short* Wh = (unsigned short*)(R + 33554432);
  unsigned short* Wl = (unsigned short*)(R + 58720256);
  unsigned short* Qh  = (unsigned short*)(R);
  unsigned short* Ql  = (unsigned short*)(R + 16777216);
  unsigned short* Kh  = (unsigned short*)(R + 33554432);
  unsigned short* Kl  = (unsigned short*)(R + 50331648);
  unsigned short* Vth = (unsigned short*)(R + 67108864);
  unsigned short* Vtl = (unsigned short*)(R + 83886080);
  unsigned short* Oh  = (unsigned short*)(ws);
  unsigned short* Ol  = (unsigned short*)(ws + 16777216);
  unsigned short* Wph = (unsigned short*)(ws + 33554432);
  unsigned short* Wpl = (unsigned short*)(ws + 41943040);

  split_bf16<<<8192,  256, 0, stream>>>(x,    xh, xl);
  split_bf16<<<12288, 256, 0, stream>>>(Wqkv, Wh, Wl);
  gemm_split<<<dim3(48, 32), 256, 0, stream>>>(xh, xl, Wh, Wl, qkv, 4096, 6144, 2048);
  rmsrope_split<<<4096, 256, 0, stream>>>(qkv, cosb, sinb, Qh, Ql, Kh, Kl);
  vtrans<<<dim3(32, NH, BATCH), 256, 0, stream>>>(qkv, Vth, Vtl);
  flash_mfma<<<dim3(SEQ / QT, NH, BATCH), 256, 0, stream>>>(Qh, Ql, Kh, Kl, Vth, Vtl, Oh, Ol);
  split_bf16<<<4096, 256, 0, stream>>>(Wproj, Wph, Wpl);
  gemm_split<<<dim3(16, 32), 256, 0, stream>>>(Oh, Ol, Wph, Wpl, out, 4096, 2048, 2048);
}